// Round 6
// baseline (77.572 us; speedup 1.0000x reference)
//
#include <hip/hip_runtime.h>

#define VEC_D     128
#define N_WORDS   100000
#define BATCH     16384
#define CTX       8
#define NS        16
#define CHUNK     100        // words per dot-block; 100000 = 1000 * 100
#define NCHUNK    1000
#define BINW      25         // words per histogram bin; 4 bins per chunk
#define NBINS     4000       // N_WORDS / BINW
#define NBINS_PAD 4096
#define CAP       256        // bucket capacity; mean fill 65.5, P(overflow) ~ 1e-40

typedef float f32x4 __attribute__((ext_vector_type(4)));
typedef int   i32x4 __attribute__((ext_vector_type(4)));

// ---------------------------------------------------------------------------
// Zero the per-bin counters (ws is poisoned 0xAA; atomics accumulate -> must
// re-zero every launch). 16*256 == NBINS_PAD exactly.
// ---------------------------------------------------------------------------
__global__ __launch_bounds__(256) void zero_kernel(int* __restrict__ counts) {
    counts[blockIdx.x * 256 + threadIdx.x] = 0;
}

// ---------------------------------------------------------------------------
// Phase A: inputs[b] = pm[doc_ids[b]] + sum_c wm[context_ids[b][c]]
// 32 lanes per row (lane r owns d = 4r..4r+3), 8 rows per 256-thread block.
// All 9 row-gathers are issued before any summing (9 KB in flight per wave).
// Also histogram-scatters this block's 128 (b,s) sample pairs into per-bin
// buckets: bin = wid/25, entry = (p<<5)|(wid%25), p = b*NS+s (< 2^18).
// Bucket order is atomic-race-dependent but each p is placed exactly once
// and writes a unique out slot -> output deterministic.
// ---------------------------------------------------------------------------
__global__ __launch_bounds__(256) void build_inputs_kernel(
    const int*   __restrict__ doc_ids,
    const int*   __restrict__ context_ids,
    const int*   __restrict__ sample_ids,
    const float* __restrict__ pm,       // [N_DOCS][128]
    const float* __restrict__ wm,       // [N_WORDS][128]
    float*       __restrict__ inputs,   // [BATCH][128]      (ws)
    int*         __restrict__ counts,   // [NBINS_PAD]       (ws)
    int*         __restrict__ bucket)   // [NBINS][CAP]      (ws)
{
    const int tid = threadIdx.x;
    const int r   = tid & 31;
    const int b   = blockIdx.x * 8 + (tid >> 5);
    const int d0  = r * 4;

    const int   doc = doc_ids[b];
    const i32x4 c0  = *(const i32x4*)&context_ids[b * CTX];
    const i32x4 c1  = *(const i32x4*)&context_ids[b * CTX + 4];

    // issue all 9 gathers back-to-back, then sum
    f32x4 g[9];
    g[0] = *(const f32x4*)&pm[(size_t)doc * VEC_D + d0];
    #pragma unroll
    for (int k = 0; k < 4; ++k)
        g[1 + k] = *(const f32x4*)&wm[(size_t)c0[k] * VEC_D + d0];
    #pragma unroll
    for (int k = 0; k < 4; ++k)
        g[5 + k] = *(const f32x4*)&wm[(size_t)c1[k] * VEC_D + d0];

    f32x4 v = g[0];
    #pragma unroll
    for (int k = 1; k < 9; ++k)
        v += g[k];
    *(f32x4*)&inputs[(size_t)b * VEC_D + d0] = v;   // coalesced 512B/row

    // histogram-scatter the 128 samples belonging to this block's 8 rows
    if (tid < 8 * NS) {
        const int p   = blockIdx.x * (8 * NS) + tid;  // flat b*NS+s
        const int w   = sample_ids[p];
        const int bin = w / BINW;                     // compiler magic-mul
        const int pos = atomicAdd(&counts[bin], 1);
        if (pos < CAP)
            bucket[bin * CAP + pos] = (p << 5) | (w % BINW);
    }
}

// ---------------------------------------------------------------------------
// Phase C: one 512-thread block per 100-word chunk. Stage outputs[:, chunk]
// into LDS tile[w][d] (pad 129): flat-indexed, coalesced 400B runs per d-row,
// nontemporal (outputs read exactly once). Staging writes conflict-free
// (consecutive w -> consecutive banks); entry reads conflict-free (lane r
// reads d = r+32k: bank (wl + r) % 32, all 32 distinct).
// Then 16 groups of 32 lanes process bucket entries: lane r gathers
// inputs[b][r+32k] (4 coalesced b32, table is L3-resident), dots against the
// LDS column, 5-shuffle butterfly reduce, lane 0 writes out[p].
// Index check (hand-verified; harness can't catch sample bugs since outputs
// is all-zero): w = bin*25 + (e&31); wl = w - 100*blockIdx; out[p] =
// sum_d inputs[p>>4][d] * outputs[d][w].
// ---------------------------------------------------------------------------
__global__ __launch_bounds__(512) void dot_kernel(
    const float* __restrict__ outputs,  // [128][N_WORDS]
    const float* __restrict__ inputs,   // [BATCH][128]
    const int*   __restrict__ counts,   // [NBINS_PAD]
    const int*   __restrict__ bucket,   // [NBINS][CAP]
    float*       __restrict__ out)      // [BATCH][NS]
{
    __shared__ float tile[CHUNK][VEC_D + 1];   // [w][d], 51.6 KB
    const int tid = threadIdx.x;
    const int t   = blockIdx.x;
    const int w0  = t * CHUNK;

    // ---- stage: 128*100 floats, 25 per thread, coalesced along w ----
    #pragma unroll
    for (int k = 0; k < 25; ++k) {
        const int flat = tid + 512 * k;
        const int d    = flat / CHUNK;           // compiler magic-mul
        const int w    = flat - d * CHUNK;
        tile[w][d] = __builtin_nontemporal_load(
            &outputs[(size_t)d * N_WORDS + w0 + w]);
    }
    __syncthreads();

    // ---- process the chunk's 4 sub-bins ----
    const int grp = tid >> 5;            // 16 groups
    const int r   = tid & 31;
    #pragma unroll
    for (int sb = 0; sb < 4; ++sb) {
        const int bin = t * 4 + sb;
        const int cnt = min(counts[bin], CAP);
        for (int i = grp; i < cnt; i += 16) {
            const int e  = bucket[bin * CAP + i];   // uniform across group
            const int p  = e >> 5;
            const int wl = sb * BINW + (e & 31);
            const int b  = p >> 4;                  // NS = 16
            float a = 0.0f;
            #pragma unroll
            for (int k = 0; k < 4; ++k)
                a += inputs[(size_t)b * VEC_D + r + 32 * k] * tile[wl][r + 32 * k];
            #pragma unroll
            for (int m = 16; m; m >>= 1)
                a += __shfl_xor(a, m, 64);
            if (r == 0)
                out[p] = a;
        }
    }
}

extern "C" void kernel_launch(void* const* d_in, const int* in_sizes, int n_in,
                              void* d_out, int out_size, void* d_ws, size_t ws_size,
                              hipStream_t stream) {
    const int*   doc_ids     = (const int*)d_in[0];
    const int*   context_ids = (const int*)d_in[1];
    const int*   sample_ids  = (const int*)d_in[2];
    const float* pm          = (const float*)d_in[3];
    const float* wm          = (const float*)d_in[4];
    const float* outputs     = (const float*)d_in[5];
    float*       out         = (float*)d_out;

    // ws layout: [inputs 8.4MB][counts 16KB][bucket 4.1MB]   (ws is ~268MB)
    float* inputs = (float*)d_ws;
    int*   counts = (int*)((char*)d_ws + (size_t)BATCH * VEC_D * sizeof(float));
    int*   bucket = counts + NBINS_PAD;

    zero_kernel<<<NBINS_PAD / 256, 256, 0, stream>>>(counts);
    build_inputs_kernel<<<BATCH / 8, 256, 0, stream>>>(
        doc_ids, context_ids, sample_ids, pm, wm, inputs, counts, bucket);
    dot_kernel<<<NCHUNK, 512, 0, stream>>>(outputs, inputs, counts, bucket, out);
}